// Round 7
// baseline (179.274 us; speedup 1.0000x reference)
//
#include <hip/hip_runtime.h>
#include <math.h>

#define N_ROWS 16384
#define M_COLS 8192
#define TPB 256
#define IT 4                        // i-rows per thread (ILP chains)
#define JT 64                       // j-tile per block (LDS staged)
#define NJ (M_COLS / JT)            // 128 j-chunks
#define NIB (N_ROWS / (TPB * IT))   // 16 i-blocks
#define PAIR_BLOCKS (NIB * NJ)      // 2048
#define EDGE_BLOCKS 2048
#define EU 4                        // edges per thread
#define GRID_BLOCKS (PAIR_BLOCKS + EDGE_BLOCKS)   // 4096

typedef float v2f __attribute__((ext_vector_type(2)));

#define C2 2.0813689810056077f      // log2(e)^2 — folded into the quadratic form

// softmax of an 8-vector held in v[], in-place; returns nothing extra
__device__ inline void softmax8(float v[8]) {
    float m = v[0];
    #pragma unroll
    for (int d = 1; d < 8; d++) m = fmaxf(m, v[d]);
    float s = 0.f;
    #pragma unroll
    for (int d = 0; d < 8; d++) { v[d] = __expf(v[d] - m); s += v[d]; }
    float inv = 1.f / s;
    #pragma unroll
    for (int d = 0; d < 8; d++) v[d] *= inv;
}

// ---------- kernel 1: everything except the final combine ----------
// even blocks: pair sum  S1 = sum_ij eg_i*exp(-dist_ij)*ec_j
//   (block softmaxes its own w-tile into LDS and its own z-rows into regs;
//    redundant recompute ~3% of pair issue — buys one fewer dispatch)
// odd  blocks: edge sum  S2 = sum_e wt_e*(gr[r]+gc[c]-dist_e)
//   (gathers RAW f32 latent rows, softmaxes inline — no staging dependency)
__global__ __launch_bounds__(TPB) void mega_kernel(
    const float* __restrict__ lz, const float* __restrict__ gr,
    const float* __restrict__ lw, const float* __restrict__ gc,
    const float* __restrict__ wt,
    const int* __restrict__ ridx, const int* __restrict__ cidx, int E,
    double* __restrict__ pair_part, double* __restrict__ edge_part)
{
    __shared__ float  sw[JT * 8];    // softmaxed w tile [JT][8]
    __shared__ float  swq[JT];       // C2*||w_j||^2
    __shared__ float  sec[JT];       // exp(gamma_cols[j])
    __shared__ double sred[TPB];

    const int t   = threadIdx.x;
    const int bid = blockIdx.x;
    const int rid = bid >> 1;

    if ((bid & 1) == 0) {
        // ================= PAIR ROLE =================
        const int ib = rid / NJ;
        const int jb = rid - ib * NJ;
        const int j0 = jb * JT;

        // in-block w-tile prep: threads 0..63 softmax one w row each
        if (t < JT) {
            const float4* wp = (const float4*)(lw + (size_t)(j0 + t) * 8);
            float4 a = wp[0], b = wp[1];
            float v[8] = {a.x, a.y, a.z, a.w, b.x, b.y, b.z, b.w};
            softmax8(v);
            float sq = 0.f;
            #pragma unroll
            for (int d = 0; d < 8; d++) {
                sw[t * 8 + d] = v[d];
                sq = fmaf(v[d], v[d], sq);
            }
            swq[t] = C2 * sq;
            sec[t] = __expf(gc[j0 + t]);
        }

        // in-block z-row prep: 4 rows per thread, softmax + scale by -2*C2
        v2f  zi[IT][4];
        float zzi[IT], acc[IT];
        const int ibase = ib * (TPB * IT);
        #pragma unroll
        for (int k = 0; k < IT; k++) {
            int i = ibase + k * TPB + t;
            const float4* zp = (const float4*)(lz + (size_t)i * 8);
            float4 a = zp[0], b = zp[1];
            float v[8] = {a.x, a.y, a.z, a.w, b.x, b.y, b.z, b.w};
            softmax8(v);
            float sq = 0.f;
            #pragma unroll
            for (int d = 0; d < 8; d++) sq = fmaf(v[d], v[d], sq);
            zi[k][0] = (v2f){-2.f * C2 * v[0], -2.f * C2 * v[1]};
            zi[k][1] = (v2f){-2.f * C2 * v[2], -2.f * C2 * v[3]};
            zi[k][2] = (v2f){-2.f * C2 * v[4], -2.f * C2 * v[5]};
            zi[k][3] = (v2f){-2.f * C2 * v[6], -2.f * C2 * v[7]};
            zzi[k] = C2 * sq;
            acc[k] = 0.f;
        }
        __syncthreads();

        // inner loop: byte-identical structure to round 6 (validated, 100 µs)
        const float4* s4 = (const float4*)sw;
        for (int j = 0; j < JT; j++) {
            float4 wa = s4[j * 2];
            float4 wb = s4[j * 2 + 1];
            v2f w01 = {wa.x, wa.y}, w23 = {wa.z, wa.w};
            v2f w45 = {wb.x, wb.y}, w67 = {wb.z, wb.w};
            float wq = swq[j];
            float e  = sec[j];
            #pragma unroll
            for (int k = 0; k < IT; k++) {
                v2f p = {zzi[k], wq};
                p = __builtin_elementwise_fma(zi[k][0], w01, p);
                p = __builtin_elementwise_fma(zi[k][1], w23, p);
                p = __builtin_elementwise_fma(zi[k][2], w45, p);
                p = __builtin_elementwise_fma(zi[k][3], w67, p);
                float sq = fmaxf(p.x + p.y, 0.f);
                float d, pr;
                asm("v_sqrt_f32 %0, %1" : "=v"(d) : "v"(sq));
                asm("v_exp_f32 %0, -%1" : "=v"(pr) : "v"(d));  // 2^(-d') = e^(-dist)
                acc[k] = fmaf(e, pr, acc[k]);
            }
        }

        double tp = 0.0;
        #pragma unroll
        for (int k = 0; k < IT; k++) {
            int i = ibase + k * TPB + t;
            tp += (double)__expf(gr[i]) * (double)acc[k];
        }

        sred[t] = tp;
        __syncthreads();
        for (int s = TPB / 2; s > 0; s >>= 1) {
            if (t < s) sred[t] += sred[t + s];
            __syncthreads();
        }
        if (t == 0) pair_part[rid] = sred[0];
    } else {
        // ================= EDGE ROLE =================
        const int tid = rid * TPB + t;
        const int e0 = tid * EU;                      // E % 4 == 0
        double local = 0.0;
        if (e0 < E) {
            int4   rr  = *(const int4*)(ridx + e0);
            int4   cc  = *(const int4*)(cidx + e0);
            float4 wt4 = *(const float4*)(wt + e0);
            int   r[EU]  = {rr.x, rr.y, rr.z, rr.w};
            int   c[EU]  = {cc.x, cc.y, cc.z, cc.w};
            float wv[EU] = {wt4.x, wt4.y, wt4.z, wt4.w};
            // two half-batches of 2 edges: caps live row-regs at ~32 VGPR
            #pragma unroll
            for (int half = 0; half < 2; half++) {
                float4 za[2], zb[2], wa4[2], wb4[2];
                float grv[2], gcv[2];
                #pragma unroll
                for (int u2 = 0; u2 < 2; u2++) {
                    int u = half * 2 + u2;
                    const float4* zp = (const float4*)(lz + (size_t)r[u] * 8);
                    const float4* wp = (const float4*)(lw + (size_t)c[u] * 8);
                    za[u2] = zp[0]; zb[u2] = zp[1];
                    wa4[u2] = wp[0]; wb4[u2] = wp[1];
                    grv[u2] = gr[r[u]];
                    gcv[u2] = gc[c[u]];
                }
                #pragma unroll
                for (int u2 = 0; u2 < 2; u2++) {
                    int u = half * 2 + u2;
                    float vz[8] = {za[u2].x, za[u2].y, za[u2].z, za[u2].w,
                                   zb[u2].x, zb[u2].y, zb[u2].z, zb[u2].w};
                    float vw[8] = {wa4[u2].x, wa4[u2].y, wa4[u2].z, wa4[u2].w,
                                   wb4[u2].x, wb4[u2].y, wb4[u2].z, wb4[u2].w};
                    softmax8(vz);
                    softmax8(vw);
                    float s = 0.f;
                    #pragma unroll
                    for (int qd = 0; qd < 8; qd++) {
                        float f = vz[qd] - vw[qd];
                        s = fmaf(f, f, s);
                    }
                    float dist;
                    asm("v_sqrt_f32 %0, %1" : "=v"(dist) : "v"(s));
                    local += (double)(wv[u] * (grv[u2] + gcv[u2] - dist));
                }
            }
        }
        sred[t] = local;
        __syncthreads();
        for (int s2 = TPB / 2; s2 > 0; s2 >>= 1) {
            if (t < s2) sred[t] += sred[t + s2];
            __syncthreads();
        }
        if (t == 0) edge_part[rid] = sred[0];
    }
}

// ---------- kernel 2: final deterministic combine ----------
__global__ __launch_bounds__(TPB) void final_kernel(
    const double* __restrict__ pp, int np,
    const double* __restrict__ ep, int ne,
    float* __restrict__ out)
{
    __shared__ double sred[TPB];
    const int t = threadIdx.x;
    double s1 = 0.0, s2 = 0.0;
    for (int i = t; i < np; i += TPB) s1 += pp[i];
    for (int i = t; i < ne; i += TPB) s2 += ep[i];
    sred[t] = s1;
    __syncthreads();
    for (int s = TPB / 2; s > 0; s >>= 1) {
        if (t < s) sred[t] += sred[t + s];
        __syncthreads();
    }
    double pair_sum = sred[0];
    __syncthreads();
    sred[t] = s2;
    __syncthreads();
    for (int s = TPB / 2; s > 0; s >>= 1) {
        if (t < s) sred[t] += sred[t + s];
        __syncthreads();
    }
    if (t == 0) {
        double edge_sum = sred[0];
        double cf = exp(-1.0e-6);   // exp(-EPS) factored out of the pair term
        out[0] = (float)(cf * pair_sum - edge_sum);
    }
}

extern "C" void kernel_launch(void* const* d_in, const int* in_sizes, int n_in,
                              void* d_out, int out_size, void* d_ws, size_t ws_size,
                              hipStream_t stream)
{
    const float* gamma_rows = (const float*)d_in[0];   // [N]
    const float* gamma_cols = (const float*)d_in[1];   // [M]
    const float* latent_z   = (const float*)d_in[2];   // [N,8]
    const float* latent_w   = (const float*)d_in[3];   // [M,8]
    const float* weights    = (const float*)d_in[4];   // [E]
    const int*   rows_idx   = (const int*)d_in[5];     // [E]
    const int*   col_idx    = (const int*)d_in[6];     // [E]
    float* out = (float*)d_out;
    const int E = in_sizes[4];

    // workspace: just the partials now (32 KB)
    char* base = (char*)d_ws;
    double* pair_part = (double*)base;
    double* edge_part = (double*)(base + (size_t)PAIR_BLOCKS * 8);
    (void)ws_size;

    mega_kernel<<<GRID_BLOCKS, TPB, 0, stream>>>(
        latent_z, gamma_rows, latent_w, gamma_cols,
        weights, rows_idx, col_idx, E, pair_part, edge_part);
    final_kernel<<<1, TPB, 0, stream>>>(pair_part, PAIR_BLOCKS,
                                        edge_part, EDGE_BLOCKS, out);
}

// Round 8
// 171.551 us; speedup vs baseline: 1.0450x; 1.0450x over previous
//
#include <hip/hip_runtime.h>
#include <math.h>

#define N_ROWS 16384
#define M_COLS 8192
#define TPB 256
#define IT 4                        // i-rows per thread
#define JT 64                       // j-tile per block (LDS staged)
#define JU 4                        // j-unroll: 16 independent bodies/stage
#define NJ (M_COLS / JT)            // 128 j-chunks
#define NIB (N_ROWS / (TPB * IT))   // 16 i-blocks
#define PAIR_BLOCKS (NIB * NJ)      // 2048
#define EDGE_BLOCKS 2048
#define EU 4                        // edges per thread
#define GRID_BLOCKS (PAIR_BLOCKS + EDGE_BLOCKS)   // 4096

typedef float v2f __attribute__((ext_vector_type(2)));
typedef _Float16 h8 __attribute__((ext_vector_type(8)));

#define C2 2.0813689810056077f      // log2(e)^2 — folded into the quadratic form

// ---------- kernel 1: fused row softmax for BOTH z and w ----------
__global__ __launch_bounds__(TPB) void rownorm_kernel(
    const float* __restrict__ lz, const float* __restrict__ gr,
    const float* __restrict__ lw, const float* __restrict__ gc,
    float* __restrict__ z, float* __restrict__ zz, float* __restrict__ eg,
    _Float16* __restrict__ zh,
    float* __restrict__ w, float* __restrict__ ww, float* __restrict__ ec,
    _Float16* __restrict__ wh)
{
    int gi = blockIdx.x * TPB + threadIdx.x;
    const float *src, *g;
    float *dv, *dq, *de;
    _Float16* dh;
    int i;
    if (gi < N_ROWS) { src = lz; g = gr; dv = z; dq = zz; de = eg; dh = zh; i = gi; }
    else             { src = lw; g = gc; dv = w; dq = ww; de = ec; dh = wh; i = gi - N_ROWS; }

    const float4* sp = (const float4*)(src + (size_t)i * 8);
    float4 a = sp[0], b = sp[1];
    float v[8] = {a.x, a.y, a.z, a.w, b.x, b.y, b.z, b.w};
    float m = v[0];
    #pragma unroll
    for (int d = 1; d < 8; d++) m = fmaxf(m, v[d]);
    float s = 0.f;
    #pragma unroll
    for (int d = 0; d < 8; d++) { v[d] = __expf(v[d] - m); s += v[d]; }
    float inv = 1.f / s;
    float sq = 0.f;
    h8 hv;
    #pragma unroll
    for (int d = 0; d < 8; d++) {
        v[d] *= inv;
        sq = fmaf(v[d], v[d], sq);
        hv[d] = (_Float16)v[d];
    }
    float4 o0 = {v[0], v[1], v[2], v[3]};
    float4 o1 = {v[4], v[5], v[6], v[7]};
    float4* dp = (float4*)(dv + (size_t)i * 8);
    dp[0] = o0; dp[1] = o1;
    *(h8*)(dh + (size_t)i * 8) = hv;
    dq[i] = C2 * sq;                 // pre-scaled for the exp2 trick
    de[i] = __expf(g[i]);
}

// ---------- kernel 2: fused pair + edge (role by bid&1) ----------
// pair inner loop restructured: JU=4 j-unroll -> 16 independent bodies,
// executed stage-wise (16 dots | 16 sqrt | 16 exp | 16 acc) so latency is
// hidden by ILP within one wave instead of TLP (rounds 4/6 proved TLP
// doesn't move it: 4->8 blocks/CU left dur and VALUBusy unchanged).
__global__ __launch_bounds__(TPB) void fused_kernel(
    const float* __restrict__ z, const float* __restrict__ zz,
    const float* __restrict__ eg,
    const float* __restrict__ w, const float* __restrict__ ww,
    const float* __restrict__ ec,
    const _Float16* __restrict__ zh, const _Float16* __restrict__ wh,
    const float* __restrict__ gr, const float* __restrict__ gc,
    const float* __restrict__ wt,
    const int* __restrict__ ridx, const int* __restrict__ cidx, int E,
    double* __restrict__ pair_part, double* __restrict__ edge_part)
{
    __shared__ float  sw[JT * 8];    // w tile [JT][8]
    __shared__ float  swq[JT];       // C2*||w_j||^2
    __shared__ float  sec[JT];       // exp(gamma_cols[j])
    __shared__ double sred[TPB];

    const int t   = threadIdx.x;
    const int bid = blockIdx.x;
    const int rid = bid >> 1;

    if ((bid & 1) == 0) {
        // ================= PAIR ROLE =================
        const int ib = rid / NJ;
        const int jb = rid - ib * NJ;
        const int j0 = jb * JT;

        if (t < JT * 2) ((float4*)sw)[t] = ((const float4*)(w + (size_t)j0 * 8))[t];
        if (t < JT)     { swq[t] = ww[j0 + t]; sec[t] = ec[j0 + t]; }

        // z rows pre-scaled by -2*C2: sq' = C2*(zz+ww-2dot), pure FMA chain
        v2f  zi[IT][4];
        float zzi[IT], acc[IT];
        const int ibase = ib * (TPB * IT);
        #pragma unroll
        for (int k = 0; k < IT; k++) {
            int i = ibase + k * TPB + t;
            const float4* zp = (const float4*)(z + (size_t)i * 8);
            float4 a = zp[0], b = zp[1];
            zi[k][0] = (v2f){-2.f * C2 * a.x, -2.f * C2 * a.y};
            zi[k][1] = (v2f){-2.f * C2 * a.z, -2.f * C2 * a.w};
            zi[k][2] = (v2f){-2.f * C2 * b.x, -2.f * C2 * b.y};
            zi[k][3] = (v2f){-2.f * C2 * b.z, -2.f * C2 * b.w};
            zzi[k] = zz[i];
            acc[k] = 0.f;
        }
        __syncthreads();

        const float4* s4 = (const float4*)sw;
        for (int jo = 0; jo < JT; jo += JU) {
            // stage 0: batch all LDS reads for 4 j's (one waitcnt, no
            // per-body ds_read stall)
            float4 wa[JU], wb[JU];
            float  wq[JU], ev[JU];
            #pragma unroll
            for (int u = 0; u < JU; u++) {
                wa[u] = s4[(jo + u) * 2];
                wb[u] = s4[(jo + u) * 2 + 1];
                wq[u] = swq[jo + u];
                ev[u] = sec[jo + u];
            }
            // stage 1: 16 independent dot-chains
            float sq[JU][IT];
            #pragma unroll
            for (int u = 0; u < JU; u++) {
                v2f w01 = {wa[u].x, wa[u].y}, w23 = {wa[u].z, wa[u].w};
                v2f w45 = {wb[u].x, wb[u].y}, w67 = {wb[u].z, wb[u].w};
                #pragma unroll
                for (int k = 0; k < IT; k++) {
                    v2f p = {zzi[k], wq[u]};
                    p = __builtin_elementwise_fma(zi[k][0], w01, p);
                    p = __builtin_elementwise_fma(zi[k][1], w23, p);
                    p = __builtin_elementwise_fma(zi[k][2], w45, p);
                    p = __builtin_elementwise_fma(zi[k][3], w67, p);
                    sq[u][k] = fmaxf(p.x + p.y, 0.f);
                }
            }
            // stage 2: 16 independent sqrt (trans pipe back-to-back)
            float dd[JU][IT];
            #pragma unroll
            for (int u = 0; u < JU; u++)
                #pragma unroll
                for (int k = 0; k < IT; k++)
                    asm("v_sqrt_f32 %0, %1" : "=v"(dd[u][k]) : "v"(sq[u][k]));
            // stage 3: 16 independent exp2(-x)
            float pr[JU][IT];
            #pragma unroll
            for (int u = 0; u < JU; u++)
                #pragma unroll
                for (int k = 0; k < IT; k++)
                    asm("v_exp_f32 %0, -%1" : "=v"(pr[u][k]) : "v"(dd[u][k]));
            // stage 4: accumulate (4-deep chains per k, latency-tolerant)
            #pragma unroll
            for (int u = 0; u < JU; u++)
                #pragma unroll
                for (int k = 0; k < IT; k++)
                    acc[k] = fmaf(ev[u], pr[u][k], acc[k]);
        }

        double tp = 0.0;
        #pragma unroll
        for (int k = 0; k < IT; k++) {
            int i = ibase + k * TPB + t;
            tp += (double)eg[i] * (double)acc[k];
        }

        sred[t] = tp;
        __syncthreads();
        for (int s = TPB / 2; s > 0; s >>= 1) {
            if (t < s) sred[t] += sred[t + s];
            __syncthreads();
        }
        if (t == 0) pair_part[rid] = sred[0];
    } else {
        // ================= EDGE ROLE =================
        const int tid = rid * TPB + t;
        const int e0 = tid * EU;                      // E % 4 == 0
        double local = 0.0;
        if (e0 < E) {
            int4   rr  = *(const int4*)(ridx + e0);
            int4   cc  = *(const int4*)(cidx + e0);
            float4 wt4 = *(const float4*)(wt + e0);
            int   r[EU]  = {rr.x, rr.y, rr.z, rr.w};
            int   c[EU]  = {cc.x, cc.y, cc.z, cc.w};
            float wv[EU] = {wt4.x, wt4.y, wt4.z, wt4.w};
            h8 zr[EU], wr[EU];
            float grv[EU], gcv[EU];
            #pragma unroll
            for (int u = 0; u < EU; u++) {
                zr[u]  = *(const h8*)(zh + (size_t)r[u] * 8);
                wr[u]  = *(const h8*)(wh + (size_t)c[u] * 8);
                grv[u] = gr[r[u]];
                gcv[u] = gc[c[u]];
            }
            #pragma unroll
            for (int u = 0; u < EU; u++) {
                h8 dv = zr[u] - wr[u];
                float s = 0.f;
                #pragma unroll
                for (int qd = 0; qd < 8; qd++) {
                    float f = (float)dv[qd];
                    s = fmaf(f, f, s);
                }
                float dist;
                asm("v_sqrt_f32 %0, %1" : "=v"(dist) : "v"(s));
                local += (double)(wv[u] * (grv[u] + gcv[u] - dist));
            }
        }
        sred[t] = local;
        __syncthreads();
        for (int s2 = TPB / 2; s2 > 0; s2 >>= 1) {
            if (t < s2) sred[t] += sred[t + s2];
            __syncthreads();
        }
        if (t == 0) edge_part[rid] = sred[0];
    }
}

// ---------- kernel 3: final deterministic combine ----------
__global__ __launch_bounds__(TPB) void final_kernel(
    const double* __restrict__ pp, int np,
    const double* __restrict__ ep, int ne,
    float* __restrict__ out)
{
    __shared__ double sred[TPB];
    const int t = threadIdx.x;
    double s1 = 0.0, s2 = 0.0;
    for (int i = t; i < np; i += TPB) s1 += pp[i];
    for (int i = t; i < ne; i += TPB) s2 += ep[i];
    sred[t] = s1;
    __syncthreads();
    for (int s = TPB / 2; s > 0; s >>= 1) {
        if (t < s) sred[t] += sred[t + s];
        __syncthreads();
    }
    double pair_sum = sred[0];
    __syncthreads();
    sred[t] = s2;
    __syncthreads();
    for (int s = TPB / 2; s > 0; s >>= 1) {
        if (t < s) sred[t] += sred[t + s];
        __syncthreads();
    }
    if (t == 0) {
        double edge_sum = sred[0];
        double cf = exp(-1.0e-6);   // exp(-EPS) factored out of the pair term
        out[0] = (float)(cf * pair_sum - edge_sum);
    }
}

extern "C" void kernel_launch(void* const* d_in, const int* in_sizes, int n_in,
                              void* d_out, int out_size, void* d_ws, size_t ws_size,
                              hipStream_t stream)
{
    const float* gamma_rows = (const float*)d_in[0];   // [N]
    const float* gamma_cols = (const float*)d_in[1];   // [M]
    const float* latent_z   = (const float*)d_in[2];   // [N,8]
    const float* latent_w   = (const float*)d_in[3];   // [M,8]
    const float* weights    = (const float*)d_in[4];   // [E]
    const int*   rows_idx   = (const int*)d_in[5];     // [E]
    const int*   col_idx    = (const int*)d_in[6];     // [E]
    float* out = (float*)d_out;
    const int E = in_sizes[4];

    // workspace layout (segments 256B-aligned); total ~1.4 MB
    char* base = (char*)d_ws;
    size_t off = 0;
    float* z  = (float*)(base + off); off += (size_t)N_ROWS * 8 * 4;
    float* zz = (float*)(base + off); off += (size_t)N_ROWS * 4;
    float* eg = (float*)(base + off); off += (size_t)N_ROWS * 4;
    float* w  = (float*)(base + off); off += (size_t)M_COLS * 8 * 4;
    float* ww = (float*)(base + off); off += (size_t)M_COLS * 4;
    float* ec = (float*)(base + off); off += (size_t)M_COLS * 4;
    _Float16* zh = (_Float16*)(base + off); off += (size_t)N_ROWS * 8 * 2;
    _Float16* wh = (_Float16*)(base + off); off += (size_t)M_COLS * 8 * 2;
    double* pair_part = (double*)(base + off); off += (size_t)PAIR_BLOCKS * 8;
    double* edge_part = (double*)(base + off); off += (size_t)EDGE_BLOCKS * 8;
    (void)ws_size;

    rownorm_kernel<<<(N_ROWS + M_COLS) / TPB, TPB, 0, stream>>>(
        latent_z, gamma_rows, latent_w, gamma_cols,
        z, zz, eg, zh, w, ww, ec, wh);
    fused_kernel<<<GRID_BLOCKS, TPB, 0, stream>>>(
        z, zz, eg, w, ww, ec, zh, wh, gamma_rows, gamma_cols,
        weights, rows_idx, col_idx, E, pair_part, edge_part);
    final_kernel<<<1, TPB, 0, stream>>>(pair_part, PAIR_BLOCKS,
                                        edge_part, EDGE_BLOCKS, out);
}

// Round 9
// 157.622 us; speedup vs baseline: 1.1374x; 1.0884x over previous
//
#include <hip/hip_runtime.h>
#include <math.h>

#define N_ROWS 16384
#define M_COLS 8192
#define TPB 256
#define IT 4                        // i-rows per thread
#define JT 64                       // j-tile per block
#define JU 4                        // j-unroll (staged bodies)
#define NJ (M_COLS / JT)            // 128 j-chunks
#define NIBH 8                      // i-blocks per HALF (A/B split)
#define PAIRA_BLOCKS (NIBH * NJ)    // 1024
#define PAIRB_BLOCKS (NIBH * NJ)    // 1024
#define EDGE_BLOCKS 2048
#define EU 4
#define FUSEDA_BLOCKS (PAIRA_BLOCKS + EDGE_BLOCKS)  // 3072

typedef float v2f __attribute__((ext_vector_type(2)));
typedef _Float16 h8 __attribute__((ext_vector_type(8)));

#define C2 2.0813689810056077f      // log2(e)^2 — folded into the quadratic form

// ---------- kernel 1: fused row softmax for BOTH z and w ----------
__global__ __launch_bounds__(TPB) void rownorm_kernel(
    const float* __restrict__ lz, const float* __restrict__ gr,
    const float* __restrict__ lw, const float* __restrict__ gc,
    float* __restrict__ z, float* __restrict__ zz, float* __restrict__ eg,
    _Float16* __restrict__ zh,
    float* __restrict__ w, float* __restrict__ ww, float* __restrict__ ec,
    _Float16* __restrict__ wh)
{
    int gi = blockIdx.x * TPB + threadIdx.x;
    const float *src, *g;
    float *dv, *dq, *de;
    _Float16* dh;
    int i;
    if (gi < N_ROWS) { src = lz; g = gr; dv = z; dq = zz; de = eg; dh = zh; i = gi; }
    else             { src = lw; g = gc; dv = w; dq = ww; de = ec; dh = wh; i = gi - N_ROWS; }

    const float4* sp = (const float4*)(src + (size_t)i * 8);
    float4 a = sp[0], b = sp[1];
    float v[8] = {a.x, a.y, a.z, a.w, b.x, b.y, b.z, b.w};
    float m = v[0];
    #pragma unroll
    for (int d = 1; d < 8; d++) m = fmaxf(m, v[d]);
    float s = 0.f;
    #pragma unroll
    for (int d = 0; d < 8; d++) { v[d] = __expf(v[d] - m); s += v[d]; }
    float inv = 1.f / s;
    float sq = 0.f;
    h8 hv;
    #pragma unroll
    for (int d = 0; d < 8; d++) {
        v[d] *= inv;
        sq = fmaf(v[d], v[d], sq);
        hv[d] = (_Float16)v[d];
    }
    float4 o0 = {v[0], v[1], v[2], v[3]};
    float4 o1 = {v[4], v[5], v[6], v[7]};
    float4* dp = (float4*)(dv + (size_t)i * 8);
    dp[0] = o0; dp[1] = o1;
    *(h8*)(dh + (size_t)i * 8) = hv;
    dq[i] = C2 * sq;                 // pre-scaled for the exp2 trick
    de[i] = __expf(g[i]);
}

// ---------- kernel 2: pairA (uniform-global w, NO LDS in loop) + edge ----
// A/B experiment, variant A: w rows / ww / ec are read with wave-uniform
// indices straight from global -> compiler can use s_load/SGPR broadcast
// (or L1-broadcast vector loads) -> the per-CU DS pipe is OUT of the loop.
__global__ __launch_bounds__(TPB) void fusedA_kernel(
    const float* __restrict__ z, const float* __restrict__ zz,
    const float* __restrict__ eg,
    const float* __restrict__ w, const float* __restrict__ ww,
    const float* __restrict__ ec,
    const _Float16* __restrict__ zh, const _Float16* __restrict__ wh,
    const float* __restrict__ gr, const float* __restrict__ gc,
    const float* __restrict__ wt,
    const int* __restrict__ ridx, const int* __restrict__ cidx, int E,
    double* __restrict__ pair_part, double* __restrict__ edge_part)
{
    __shared__ double sred[TPB];
    const int t   = threadIdx.x;
    const int bid = blockIdx.x;

    if (bid < PAIRA_BLOCKS) {
        // ================= PAIR ROLE (variant A) =================
        const int rid = bid;
        const int ib = rid / NJ;            // 0..7 (first i-half)
        const int jb = rid - ib * NJ;
        const int j0 = jb * JT;

        float zi[IT][8], zzi[IT], acc[IT];
        const int ibase = ib * (TPB * IT);
        #pragma unroll
        for (int k = 0; k < IT; k++) {
            int i = ibase + k * TPB + t;
            const float4* zp = (const float4*)(z + (size_t)i * 8);
            float4 a = zp[0], b = zp[1];
            zi[k][0] = -2.f * C2 * a.x; zi[k][1] = -2.f * C2 * a.y;
            zi[k][2] = -2.f * C2 * a.z; zi[k][3] = -2.f * C2 * a.w;
            zi[k][4] = -2.f * C2 * b.x; zi[k][5] = -2.f * C2 * b.y;
            zi[k][6] = -2.f * C2 * b.z; zi[k][7] = -2.f * C2 * b.w;
            zzi[k] = zz[i];
            acc[k] = 0.f;
        }

        const float* wb  = w  + (size_t)j0 * 8;   // uniform base
        const float* wqb = ww + j0;
        const float* ecb = ec + j0;

        for (int jo = 0; jo < JT; jo += JU) {
            // stage 0: uniform loads (scalar-pipe candidates)
            float wv[JU][8], wq[JU], ev[JU];
            #pragma unroll
            for (int u = 0; u < JU; u++) {
                #pragma unroll
                for (int d = 0; d < 8; d++) wv[u][d] = wb[(jo + u) * 8 + d];
                wq[u] = wqb[jo + u];
                ev[u] = ecb[jo + u];
            }
            // stage 1: 16 independent dot-chains (v_fma with SGPR src)
            float sq[JU][IT];
            #pragma unroll
            for (int u = 0; u < JU; u++) {
                #pragma unroll
                for (int k = 0; k < IT; k++) {
                    float p = zzi[k] + wq[u];
                    #pragma unroll
                    for (int d = 0; d < 8; d++) p = fmaf(zi[k][d], wv[u][d], p);
                    sq[u][k] = fmaxf(p, 0.f);
                }
            }
            // stage 2: 16 sqrt
            float dd[JU][IT];
            #pragma unroll
            for (int u = 0; u < JU; u++)
                #pragma unroll
                for (int k = 0; k < IT; k++)
                    asm("v_sqrt_f32 %0, %1" : "=v"(dd[u][k]) : "v"(sq[u][k]));
            // stage 3: 16 exp2(-x)
            float pr[JU][IT];
            #pragma unroll
            for (int u = 0; u < JU; u++)
                #pragma unroll
                for (int k = 0; k < IT; k++)
                    asm("v_exp_f32 %0, -%1" : "=v"(pr[u][k]) : "v"(dd[u][k]));
            // stage 4: accumulate
            #pragma unroll
            for (int u = 0; u < JU; u++)
                #pragma unroll
                for (int k = 0; k < IT; k++)
                    acc[k] = fmaf(ev[u], pr[u][k], acc[k]);
        }

        double tp = 0.0;
        #pragma unroll
        for (int k = 0; k < IT; k++) {
            int i = ibase + k * TPB + t;
            tp += (double)eg[i] * (double)acc[k];
        }
        sred[t] = tp;
        __syncthreads();
        for (int s = TPB / 2; s > 0; s >>= 1) {
            if (t < s) sred[t] += sred[t + s];
            __syncthreads();
        }
        if (t == 0) pair_part[rid] = sred[0];
    } else {
        // ================= EDGE ROLE =================
        const int er = bid - PAIRA_BLOCKS;           // 0..2047
        const int tid = er * TPB + t;
        const int e0 = tid * EU;                     // E % 4 == 0
        double local = 0.0;
        if (e0 < E) {
            int4   rr  = *(const int4*)(ridx + e0);
            int4   cc  = *(const int4*)(cidx + e0);
            float4 wt4 = *(const float4*)(wt + e0);
            int   r[EU]  = {rr.x, rr.y, rr.z, rr.w};
            int   c[EU]  = {cc.x, cc.y, cc.z, cc.w};
            float wv[EU] = {wt4.x, wt4.y, wt4.z, wt4.w};
            h8 zr[EU], wr[EU];
            float grv[EU], gcv[EU];
            #pragma unroll
            for (int u = 0; u < EU; u++) {
                zr[u]  = *(const h8*)(zh + (size_t)r[u] * 8);
                wr[u]  = *(const h8*)(wh + (size_t)c[u] * 8);
                grv[u] = gr[r[u]];
                gcv[u] = gc[c[u]];
            }
            #pragma unroll
            for (int u = 0; u < EU; u++) {
                h8 dv = zr[u] - wr[u];
                float s = 0.f;
                #pragma unroll
                for (int qd = 0; qd < 8; qd++) {
                    float f = (float)dv[qd];
                    s = fmaf(f, f, s);
                }
                float dist;
                asm("v_sqrt_f32 %0, %1" : "=v"(dist) : "v"(s));
                local += (double)(wv[u] * (grv[u] + gcv[u] - dist));
            }
        }
        sred[t] = local;
        __syncthreads();
        for (int s2 = TPB / 2; s2 > 0; s2 >>= 1) {
            if (t < s2) sred[t] += sred[t + s2];
            __syncthreads();
        }
        if (t == 0) edge_part[er] = sred[0];
    }
}

// ---------- kernel 3: pairB — round-8 LDS body, second i-half (control) --
__global__ __launch_bounds__(TPB) void pairB_kernel(
    const float* __restrict__ z, const float* __restrict__ zz,
    const float* __restrict__ eg,
    const float* __restrict__ w, const float* __restrict__ ww,
    const float* __restrict__ ec,
    double* __restrict__ pair_part)
{
    __shared__ float  sw[JT * 8];
    __shared__ float  swq[JT];
    __shared__ float  sec[JT];
    __shared__ double sred[TPB];

    const int t   = threadIdx.x;
    const int rid = blockIdx.x;
    const int ib  = NIBH + rid / NJ;        // 8..15 (second i-half)
    const int jb  = rid - (rid / NJ) * NJ;
    const int j0  = jb * JT;

    if (t < JT * 2) ((float4*)sw)[t] = ((const float4*)(w + (size_t)j0 * 8))[t];
    if (t < JT)     { swq[t] = ww[j0 + t]; sec[t] = ec[j0 + t]; }

    v2f  zi[IT][4];
    float zzi[IT], acc[IT];
    const int ibase = ib * (TPB * IT);
    #pragma unroll
    for (int k = 0; k < IT; k++) {
        int i = ibase + k * TPB + t;
        const float4* zp = (const float4*)(z + (size_t)i * 8);
        float4 a = zp[0], b = zp[1];
        zi[k][0] = (v2f){-2.f * C2 * a.x, -2.f * C2 * a.y};
        zi[k][1] = (v2f){-2.f * C2 * a.z, -2.f * C2 * a.w};
        zi[k][2] = (v2f){-2.f * C2 * b.x, -2.f * C2 * b.y};
        zi[k][3] = (v2f){-2.f * C2 * b.z, -2.f * C2 * b.w};
        zzi[k] = zz[i];
        acc[k] = 0.f;
    }
    __syncthreads();

    const float4* s4 = (const float4*)sw;
    for (int jo = 0; jo < JT; jo += JU) {
        float4 wa[JU], wb4[JU];
        float  wq[JU], ev[JU];
        #pragma unroll
        for (int u = 0; u < JU; u++) {
            wa[u] = s4[(jo + u) * 2];
            wb4[u] = s4[(jo + u) * 2 + 1];
            wq[u] = swq[jo + u];
            ev[u] = sec[jo + u];
        }
        float sq[JU][IT];
        #pragma unroll
        for (int u = 0; u < JU; u++) {
            v2f w01 = {wa[u].x, wa[u].y}, w23 = {wa[u].z, wa[u].w};
            v2f w45 = {wb4[u].x, wb4[u].y}, w67 = {wb4[u].z, wb4[u].w};
            #pragma unroll
            for (int k = 0; k < IT; k++) {
                v2f p = {zzi[k], wq[u]};
                p = __builtin_elementwise_fma(zi[k][0], w01, p);
                p = __builtin_elementwise_fma(zi[k][1], w23, p);
                p = __builtin_elementwise_fma(zi[k][2], w45, p);
                p = __builtin_elementwise_fma(zi[k][3], w67, p);
                sq[u][k] = fmaxf(p.x + p.y, 0.f);
            }
        }
        float dd[JU][IT];
        #pragma unroll
        for (int u = 0; u < JU; u++)
            #pragma unroll
            for (int k = 0; k < IT; k++)
                asm("v_sqrt_f32 %0, %1" : "=v"(dd[u][k]) : "v"(sq[u][k]));
        float pr[JU][IT];
        #pragma unroll
        for (int u = 0; u < JU; u++)
            #pragma unroll
            for (int k = 0; k < IT; k++)
                asm("v_exp_f32 %0, -%1" : "=v"(pr[u][k]) : "v"(dd[u][k]));
        #pragma unroll
        for (int u = 0; u < JU; u++)
            #pragma unroll
            for (int k = 0; k < IT; k++)
                acc[k] = fmaf(ev[u], pr[u][k], acc[k]);
    }

    double tp = 0.0;
    #pragma unroll
    for (int k = 0; k < IT; k++) {
        int i = ibase + k * TPB + t;
        tp += (double)eg[i] * (double)acc[k];
    }
    sred[t] = tp;
    __syncthreads();
    for (int s = TPB / 2; s > 0; s >>= 1) {
        if (t < s) sred[t] += sred[t + s];
        __syncthreads();
    }
    if (t == 0) pair_part[PAIRA_BLOCKS + rid] = sred[0];
}

// ---------- kernel 4: final deterministic combine ----------
__global__ __launch_bounds__(TPB) void final_kernel(
    const double* __restrict__ pp, int np,
    const double* __restrict__ ep, int ne,
    float* __restrict__ out)
{
    __shared__ double sred[TPB];
    const int t = threadIdx.x;
    double s1 = 0.0, s2 = 0.0;
    for (int i = t; i < np; i += TPB) s1 += pp[i];
    for (int i = t; i < ne; i += TPB) s2 += ep[i];
    sred[t] = s1;
    __syncthreads();
    for (int s = TPB / 2; s > 0; s >>= 1) {
        if (t < s) sred[t] += sred[t + s];
        __syncthreads();
    }
    double pair_sum = sred[0];
    __syncthreads();
    sred[t] = s2;
    __syncthreads();
    for (int s = TPB / 2; s > 0; s >>= 1) {
        if (t < s) sred[t] += sred[t + s];
        __syncthreads();
    }
    if (t == 0) {
        double edge_sum = sred[0];
        double cf = exp(-1.0e-6);   // exp(-EPS) factored out of the pair term
        out[0] = (float)(cf * pair_sum - edge_sum);
    }
}

extern "C" void kernel_launch(void* const* d_in, const int* in_sizes, int n_in,
                              void* d_out, int out_size, void* d_ws, size_t ws_size,
                              hipStream_t stream)
{
    const float* gamma_rows = (const float*)d_in[0];   // [N]
    const float* gamma_cols = (const float*)d_in[1];   // [M]
    const float* latent_z   = (const float*)d_in[2];   // [N,8]
    const float* latent_w   = (const float*)d_in[3];   // [M,8]
    const float* weights    = (const float*)d_in[4];   // [E]
    const int*   rows_idx   = (const int*)d_in[5];     // [E]
    const int*   col_idx    = (const int*)d_in[6];     // [E]
    float* out = (float*)d_out;
    const int E = in_sizes[4];

    char* base = (char*)d_ws;
    size_t off = 0;
    float* z  = (float*)(base + off); off += (size_t)N_ROWS * 8 * 4;
    float* zz = (float*)(base + off); off += (size_t)N_ROWS * 4;
    float* eg = (float*)(base + off); off += (size_t)N_ROWS * 4;
    float* w  = (float*)(base + off); off += (size_t)M_COLS * 8 * 4;
    float* ww = (float*)(base + off); off += (size_t)M_COLS * 4;
    float* ec = (float*)(base + off); off += (size_t)M_COLS * 4;
    _Float16* zh = (_Float16*)(base + off); off += (size_t)N_ROWS * 8 * 2;
    _Float16* wh = (_Float16*)(base + off); off += (size_t)M_COLS * 8 * 2;
    double* pair_part = (double*)(base + off); off += (size_t)(PAIRA_BLOCKS + PAIRB_BLOCKS) * 8;
    double* edge_part = (double*)(base + off); off += (size_t)EDGE_BLOCKS * 8;
    (void)ws_size;

    rownorm_kernel<<<(N_ROWS + M_COLS) / TPB, TPB, 0, stream>>>(
        latent_z, gamma_rows, latent_w, gamma_cols,
        z, zz, eg, zh, w, ww, ec, wh);
    fusedA_kernel<<<FUSEDA_BLOCKS, TPB, 0, stream>>>(
        z, zz, eg, w, ww, ec, zh, wh, gamma_rows, gamma_cols,
        weights, rows_idx, col_idx, E, pair_part, edge_part);
    pairB_kernel<<<PAIRB_BLOCKS, TPB, 0, stream>>>(
        z, zz, eg, w, ww, ec, pair_part);
    final_kernel<<<1, TPB, 0, stream>>>(pair_part, PAIRA_BLOCKS + PAIRB_BLOCKS,
                                        edge_part, EDGE_BLOCKS, out);
}